// Round 7
// baseline (6146.795 us; speedup 1.0000x reference)
//
#include <hip/hip_runtime.h>
#include <cstdint>
#include <cstddef>

typedef unsigned long long ull;
typedef unsigned int uint32;

// B=16, T=128, K=1024, D=768, KP=102
// Persistent scan, batch-quad design (p=4): each block serves 4 batches with a
// 16-col matrix slice -> chip matrix traffic 24 MB/step (was 96), grid 528
// (~2 blocks/CU, 8 waves for latency hiding).
//  fwd: bids 0..255   = quad g (4 batches) x slice s (16 cols), expT bf16
//  vit: bids 256..511 = quad g x slice s (16 cols), tr fp32 (exact)
//  approx: bids 512..527 block-local.
// All cross-block state via sc0sc1 bypass (LLC); barrier = wave0 vmcnt drain +
// RELAXED add + RELAXED spin; all bypass stores issued by wave 0.

// ---- workspace layout (float offsets) ----
#define OFF_EM    ((size_t)0)         // emission   2048*1024 f32
#define OFF_TR    ((size_t)2097152)   // transition 1024*1024 f32
#define OFF_EXPTB ((size_t)3145728)   // expTb      1024*1024 bf16 (ushort)
#define OFF_UPP   ((size_t)3670016)   // u ping-pong 2*16*1024
#define OFF_APP   ((size_t)3702784)   // av ping-pong 2*16*1024
#define OFF_ULST  ((size_t)3735552)   // u at t=tb   16*1024
#define OFF_ALST  ((size_t)3751936)   // av at t=tb  16*1024
#define OFF_UALST ((size_t)3768320)   // ua at t=tb  16*102
#define OFF_ETOP  ((size_t)3769952)   // em_top      2048*102
#define OFF_ITOP  ((size_t)3978848)   // top_idx     2048*102 (int)
#define OFF_RMAX  ((size_t)4187744)   // row_max     2048
#define OFF_RLSE  ((size_t)4189792)   // row_lse     2048
#define OFF_SMP   ((size_t)4191840)   // sm_pred     2048 (int)
#define OFF_BP    ((size_t)4193888)   // bp          128*16*1024 (int)
#define OFF_BAR   ((size_t)6291040)   // barrier counters (64 uints)

__device__ __forceinline__ unsigned short f2bf(float f) {
  uint32 u = __builtin_bit_cast(uint32, f);
  u = (u + 0x7fffu + ((u >> 16) & 1u)) >> 16;
  return (unsigned short)u;
}
__device__ __forceinline__ float bflo(uint32 w) {
  return __builtin_bit_cast(float, w << 16);
}
__device__ __forceinline__ float bfhi(uint32 w) {
  return __builtin_bit_cast(float, w & 0xffff0000u);
}

// ---------------- GEMM: [x_emb; state] (3072x768) @ state^T -> 3072x1024 ----
__global__ __launch_bounds__(256) void gemm_kernel(
    const float* __restrict__ x, const float* __restrict__ stm,
    float* __restrict__ emission, float* __restrict__ transition,
    unsigned short* __restrict__ expTb) {
  __shared__ float As[16][68];
  __shared__ float Bs[16][68];
  const int tid = threadIdx.x;
  const int tx = tid & 15, ty = tid >> 4;
  const int m0 = blockIdx.x * 64, n0 = blockIdx.y * 64;
  const int lr = tid >> 2;
  const int lc = (tid & 3) << 2;
  float acc[4][4] = {};
  const float* aptr;
  {
    int gr = m0 + lr;
    aptr = (gr < 2048) ? (x + (size_t)gr * 768) : (stm + (size_t)(gr - 2048) * 768);
  }
  const float* bptr = stm + (size_t)(n0 + lr) * 768;
  for (int k0 = 0; k0 < 768; k0 += 16) {
    float4 a4 = *(const float4*)(aptr + k0 + lc);
    float4 b4 = *(const float4*)(bptr + k0 + lc);
    __syncthreads();
    As[lc + 0][lr] = a4.x; As[lc + 1][lr] = a4.y; As[lc + 2][lr] = a4.z; As[lc + 3][lr] = a4.w;
    Bs[lc + 0][lr] = b4.x; Bs[lc + 1][lr] = b4.y; Bs[lc + 2][lr] = b4.z; Bs[lc + 3][lr] = b4.w;
    __syncthreads();
#pragma unroll
    for (int kk = 0; kk < 16; ++kk) {
      float a[4], b[4];
#pragma unroll
      for (int q = 0; q < 4; ++q) a[q] = As[kk][ty * 4 + q];
#pragma unroll
      for (int q = 0; q < 4; ++q) b[q] = Bs[kk][tx * 4 + q];
#pragma unroll
      for (int i2 = 0; i2 < 4; ++i2)
#pragma unroll
        for (int j2 = 0; j2 < 4; ++j2) acc[i2][j2] += a[i2] * b[j2];
    }
  }
  const float rs = 0.03608439182435161f;  // 1/sqrt(768)
#pragma unroll
  for (int i2 = 0; i2 < 4; ++i2) {
    int r = m0 + ty * 4 + i2;
#pragma unroll
    for (int j2 = 0; j2 < 4; ++j2) {
      int c = n0 + tx * 4 + j2;
      float v = acc[i2][j2] * rs;
      if (r < 2048) {
        emission[(size_t)r * 1024 + c] = v;
      } else {
        size_t o = (size_t)(r - 2048) * 1024 + c;
        transition[o] = v;
        expTb[o] = f2bf(expf(v));
      }
    }
  }
}

// ---------------- per-row bitonic sort -> top-102 set, max, lse, argmax ----
__global__ __launch_bounds__(256) void topk_kernel(
    const float* __restrict__ emission, float* __restrict__ em_top,
    int* __restrict__ top_idx, float* __restrict__ row_max,
    float* __restrict__ row_lse, int* __restrict__ sm_pred) {
  __shared__ float v[1024];
  __shared__ int ix[1024];
  __shared__ float rb[256];
  const int row = blockIdx.x;
  const int tid = threadIdx.x;
  const float* e = emission + (size_t)row * 1024;
  for (int p = tid; p < 1024; p += 256) { v[p] = e[p]; ix[p] = p; }
  __syncthreads();
  for (int k = 2; k <= 1024; k <<= 1) {
    for (int j = k >> 1; j > 0; j >>= 1) {
      for (int p = tid; p < 1024; p += 256) {
        int l = p ^ j;
        if (l > p) {
          float va = v[p], vb = v[l];
          int ia = ix[p], ib = ix[l];
          bool aBefore = (va > vb) || (va == vb && ia < ib);
          bool up = ((p & k) == 0);
          if (up ? !aBefore : aBefore) { v[p] = vb; v[l] = va; ix[p] = ib; ix[l] = ia; }
        }
      }
      __syncthreads();
    }
  }
  float mx = v[0];
  float s = 0.f;
  for (int p = tid; p < 1024; p += 256) s += expf(v[p] - mx);
  rb[tid] = s; __syncthreads();
  for (int w = 128; w > 0; w >>= 1) { if (tid < w) rb[tid] += rb[tid + w]; __syncthreads(); }
  if (tid == 0) {
    row_max[row] = mx;
    row_lse[row] = mx + logf(rb[0]);
    sm_pred[row] = ix[0];
  }
  for (int p = tid; p < 102; p += 256) {
    em_top[(size_t)row * 102 + p] = v[p];
    top_idx[(size_t)row * 102 + p] = ix[p];
  }
}

// ---------------- coherence helpers ----
__device__ __forceinline__ void store_bypass2(float* p, float2 v) {
  __hip_atomic_store((ull*)p, __builtin_bit_cast(ull, v),
                     __ATOMIC_RELAXED, __HIP_MEMORY_SCOPE_AGENT);
}
__device__ __forceinline__ void store_bypass_i2(int* p, int2 v) {
  __hip_atomic_store((ull*)p, __builtin_bit_cast(ull, v),
                     __ATOMIC_RELAXED, __HIP_MEMORY_SCOPE_AGENT);
}
__device__ __forceinline__ float load_bypass_f(const float* p) {
  return __hip_atomic_load(p, __ATOMIC_RELAXED, __HIP_MEMORY_SCOPE_AGENT);
}
__device__ __forceinline__ int load_bypass_i(const int* p) {
  return __hip_atomic_load(p, __ATOMIC_RELAXED, __HIP_MEMORY_SCOPE_AGENT);
}

// Barrier: wave0 vmcnt drain (covers all bypass stores — issued by wave 0),
// RELAXED add + RELAXED spin. No cache maintenance anywhere.
__device__ __forceinline__ void group_barrier(unsigned* ctr, unsigned target) {
  __syncthreads();
  if (threadIdx.x == 0) {
    asm volatile("s_waitcnt vmcnt(0)" ::: "memory");
    __hip_atomic_fetch_add(ctr, 1u, __ATOMIC_RELAXED, __HIP_MEMORY_SCOPE_AGENT);
    while (__hip_atomic_load(ctr, __ATOMIC_RELAXED, __HIP_MEMORY_SCOPE_AGENT) < target)
      __builtin_amdgcn_s_sleep(1);
  }
  __syncthreads();
  __atomic_signal_fence(__ATOMIC_ACQUIRE);
}

// stage 4 batches' state (4096 floats = 2048 ull) into LDS
__device__ __forceinline__ void stage_quad(const float* __restrict__ src,
                                           float* __restrict__ st, int tid) {
  const ull* s8 = (const ull*)src;
  ull* l8 = (ull*)st;
#pragma unroll
  for (int m = 0; m < 8; ++m)
    l8[tid + m * 256] =
        __hip_atomic_load(s8 + tid + m * 256, __ATOMIC_RELAXED, __HIP_MEMORY_SCOPE_AGENT);
}

// ---------------- persistent scan ----
__global__ __launch_bounds__(256, 1) void scan_kernel(
    const float* __restrict__ em, const float* __restrict__ tr,
    const unsigned short* __restrict__ expTb, const float* __restrict__ em_top,
    const int* __restrict__ top_idx, const int* __restrict__ y_lens,
    float* __restrict__ u_pp, float* __restrict__ av_pp,
    float* __restrict__ u_last, float* __restrict__ av_last,
    float* __restrict__ ua_last, int* __restrict__ bp,
    unsigned* __restrict__ bars, float* __restrict__ out_crf) {
  __shared__ __align__(16) float st[4096];   // 4 batches x 1024 state
  __shared__ __align__(16) float psv[960];   // fwd: 15 x 64; vit: 7 x 64
  __shared__ __align__(16) int psi[448];     // vit: 7 x 64
  __shared__ float sua[2][102];
  __shared__ int sidxp[102], sidxc[102];
  __shared__ float aps[102];
  __shared__ int slens[16];
  __shared__ float swv[4];
  __shared__ int swi[4];
  const int bid = blockIdx.x, tid = threadIdx.x;
  if (tid < 16) slens[tid] = y_lens[tid];
  __syncthreads();

  if (bid < 256) {
    // ======== forward: quad g, slice s (16 cols, bf16 expT) ========
    const int g = bid >> 6, s = bid & 63;
    const int tl = tid & 3;          // col group (4 cols)
    const int bq = (tid >> 2) & 3;   // batch in quad
    const int h = tid >> 4;          // 0..15, rows h*64..h*64+63
    const int b = g * 4 + bq;
    const int j = s * 16 + tl * 4;
    const int tb = slens[b] - 1;
    const int lane16 = tid & 15;     // (bq,tl) id among 16
    if (h == 0) {
      const float4 e4 = *(const float4*)(em + (size_t)(b * 128) * 1024 + j);
      float4 v;
      v.x = expf(e4.x); v.y = expf(e4.y); v.z = expf(e4.z); v.w = expf(e4.w);
      float* dst = u_pp + b * 1024 + j;
      store_bypass2(dst, make_float2(v.x, v.y));
      store_bypass2(dst + 2, make_float2(v.z, v.w));
      if (tb == 0) *(float4*)(u_last + b * 1024 + j) = v;
    }
    unsigned k = 1;
    group_barrier(&bars[g], 64u * k); ++k;
    for (int t = 1; t < 128; ++t) {
      stage_quad(u_pp + ((t - 1) & 1) * 16384 + g * 4096, st, tid);
      __syncthreads();
      const float* stb = st + bq * 1024;
      float a0 = 0.f, a1 = 0.f, a2 = 0.f, a3 = 0.f;
#pragma unroll 4
      for (int i = h * 64; i < h * 64 + 64; ++i) {
        const uint2 w = *(const uint2*)(expTb + (size_t)i * 1024 + j);
        const float ui = stb[i];
        a0 += ui * bflo(w.x); a1 += ui * bfhi(w.x);
        a2 += ui * bflo(w.y); a3 += ui * bfhi(w.y);
      }
      if (h) {
        *((float4*)(psv + (h - 1) * 64 + lane16 * 4)) = make_float4(a0, a1, a2, a3);
      }
      __syncthreads();
      if (h == 0) {
#pragma unroll
        for (int q = 0; q < 15; ++q) {
          const float4 p = *((const float4*)(psv + q * 64 + lane16 * 4));
          a0 += p.x; a1 += p.y; a2 += p.z; a3 += p.w;
        }
        const float4 e4 = *(const float4*)(em + ((size_t)b * 128 + t) * 1024 + j);
        float4 v;
        v.x = a0 * expf(e4.x) * (1.0f / 1024.0f);
        v.y = a1 * expf(e4.y) * (1.0f / 1024.0f);
        v.z = a2 * expf(e4.z) * (1.0f / 1024.0f);
        v.w = a3 * expf(e4.w) * (1.0f / 1024.0f);
        float* dst = u_pp + (t & 1) * 16384 + b * 1024 + j;
        store_bypass2(dst, make_float2(v.x, v.y));
        store_bypass2(dst + 2, make_float2(v.z, v.w));
        if (t == tb) *(float4*)(u_last + b * 1024 + j) = v;
      }
      group_barrier(&bars[g], 64u * k); ++k;
    }
  } else if (bid < 512) {
    // ======== viterbi: quad g, slice s (16 cols, fp32 tr, exact) ========
    const int local = bid - 256;
    const int g = local >> 6, s = local & 63;
    const int tl = tid & 7;          // col pair
    const int bq = (tid >> 3) & 3;   // batch in quad
    const int h = tid >> 5;          // 0..7, rows h*128..h*128+127
    const int b = g * 4 + bq;
    const int j = s * 16 + tl * 2;
    const int tb = slens[b] - 1;
    const int lane32 = tid & 31;     // (bq,tl) id among 32
    if (h == 0) {
      const float2 e2 = *(const float2*)(em + (size_t)(b * 128) * 1024 + j);
      store_bypass2(av_pp + b * 1024 + j, e2);
      if (tb == 0) store_bypass2(av_last + b * 1024 + j, e2);
    }
    unsigned k = 1;
    group_barrier(&bars[8 + g], 64u * k); ++k;
    for (int t = 1; t < 128; ++t) {
      stage_quad(av_pp + ((t - 1) & 1) * 16384 + g * 4096, st, tid);
      __syncthreads();
      const float* ab = st + bq * 1024;
      float m0 = -3.0e38f, m1 = -3.0e38f;
      int x0 = 0x7fffffff, x1 = 0x7fffffff;
#pragma unroll 4
      for (int i = h * 128; i < h * 128 + 128; ++i) {
        const float2 t2 = *(const float2*)(tr + (size_t)i * 1024 + j);
        const float ai = ab[i];
        float c0 = ai + t2.x;
        float c1 = ai + t2.y;
        if (c0 > m0) { m0 = c0; x0 = i; }
        if (c1 > m1) { m1 = c1; x1 = i; }
      }
      if (h) {
        const int o = (h - 1) * 64 + lane32 * 2;
        psv[o] = m0; psv[o + 1] = m1;
        psi[o] = x0; psi[o + 1] = x1;
      }
      __syncthreads();
      if (h == 0) {
#pragma unroll
        for (int q = 0; q < 7; ++q) {
          const int o = q * 64 + lane32 * 2;
          float p0 = psv[o], p1 = psv[o + 1];
          int y0 = psi[o], y1 = psi[o + 1];
          if (p0 > m0) { m0 = p0; x0 = y0; }  // ascending h: ties keep lower i
          if (p1 > m1) { m1 = p1; x1 = y1; }
        }
        const float2 e2 = *(const float2*)(em + ((size_t)b * 128 + t) * 1024 + j);
        float2 nv = make_float2(m0 + e2.x, m1 + e2.y);
        store_bypass2(av_pp + (t & 1) * 16384 + b * 1024 + j, nv);
        store_bypass_i2(bp + (size_t)t * 16384 + b * 1024 + j, make_int2(x0, x1));
        if (t == tb) store_bypass2(av_last + b * 1024 + j, nv);
      }
      group_barrier(&bars[8 + g], 64u * k); ++k;
    }
    // ---- backtrace: vit blocks with s<4 handle batch g*4+s ----
    if (s < 4) {
      const int bb = g * 4 + s;
      const int tbb = slens[bb] - 1;
      for (int t2 = tbb + 1 + tid; t2 < 128; t2 += 256) out_crf[bb * 128 + t2] = 0.f;
      const float* al = av_last + bb * 1024;
      float bv = -3.0e38f;
      int bi = 0x7fffffff;
      for (int i = tid; i < 1024; i += 256) {
        float val = load_bypass_f(al + i);
        if (val > bv || (val == bv && i < bi)) { bv = val; bi = i; }
      }
      for (int off = 32; off > 0; off >>= 1) {
        float ov = __shfl_xor(bv, off);
        int oi = __shfl_xor(bi, off);
        if (ov > bv || (ov == bv && oi < bi)) { bv = ov; bi = oi; }
      }
      if ((tid & 63) == 0) { swv[tid >> 6] = bv; swi[tid >> 6] = bi; }
      __syncthreads();
      if (tid == 0) {
        for (int q = 1; q < 4; ++q)
          if (swv[q] > bv || (swv[q] == bv && swi[q] < bi)) { bv = swv[q]; bi = swi[q]; }
        int sx = bi;
        out_crf[bb * 128 + tbb] = (float)sx;
        for (int t2 = tbb - 1; t2 >= 0; --t2) {
          sx = load_bypass_i(bp + (size_t)(t2 + 1) * 16384 + bb * 1024 + sx);
          out_crf[bb * 128 + t2] = (float)sx;
        }
      }
    }
  } else {
    // ======== approx: one block per batch, fully block-local ========
    const int b = bid - 512;
    const int tb = slens[b] - 1;
    const int j2 = tid & 127, h2 = tid >> 7;
    if (tid < 102) {
      float v = expf(em_top[(size_t)(b * 128) * 102 + tid]);
      sua[0][tid] = v;
      if (tb == 0) ua_last[b * 102 + tid] = v;
    }
    __syncthreads();
    for (int t = 1; t < 128; ++t) {
      if (tid < 102) {
        sidxp[tid] = top_idx[((size_t)b * 128 + (t - 1)) * 102 + tid];
        sidxc[tid] = top_idx[((size_t)b * 128 + t) * 102 + tid];
      }
      __syncthreads();
      float acc2 = 0.f;
      if (j2 < 102) {
        const int col = sidxc[j2];
        const float* up = sua[(t - 1) & 1];
        for (int i = h2 * 51; i < h2 * 51 + 51; ++i)
          acc2 += up[i] * bflo((uint32)expTb[(size_t)sidxp[i] * 1024 + col]);
      }
      if (h2 == 1 && j2 < 102) aps[j2] = acc2;
      __syncthreads();
      if (h2 == 0 && j2 < 102) {
        acc2 += aps[j2];
        float e = em_top[((size_t)b * 128 + t) * 102 + j2];
        float nv = acc2 * expf(e) * (1.0f / 102.0f);
        sua[t & 1][j2] = nv;
        if (t == tb) ua_last[b * 102 + j2] = nv;
      }
      __syncthreads();
    }
  }
}

// ---------------- scalars & metrics ----
__device__ __forceinline__ float blk_sum(float v, float* rb, int tid) {
  rb[tid] = v; __syncthreads();
  for (int w = 128; w > 0; w >>= 1) { if (tid < w) rb[tid] += rb[tid + w]; __syncthreads(); }
  float r = rb[0]; __syncthreads();
  return r;
}

__global__ __launch_bounds__(256) void finalize_kernel(
    const float* __restrict__ emission, const float* __restrict__ transition,
    const float* __restrict__ u_last, const float* __restrict__ ua_last,
    const float* __restrict__ row_max, const float* __restrict__ row_lse,
    const int* __restrict__ sm_pred, const int* __restrict__ y,
    const int* __restrict__ y_lens, float* __restrict__ d_out) {
  __shared__ float rb[256];
  __shared__ float sZ[16], sZa[16], sLogy[16];
  const int tid = threadIdx.x;
  const float* out_crf = d_out + 1;
  for (int b = 0; b < 16; ++b) {
    const int tb = y_lens[b] - 1;
    float p = 0.f;
    for (int i = tid; i < 1024; i += 256) p += u_last[(size_t)b * 1024 + i];
    p = blk_sum(p, rb, tid);
    if (tid == 0) sZ[b] = logf(p) + (float)tb * 6.931471805599453f;  // ln(1024)
    float q = 0.f;
    for (int i = tid; i < 102; i += 256) q += ua_last[(size_t)b * 102 + i];
    q = blk_sum(q, rb, tid);
    if (tid == 0) sZa[b] = logf(q) + (float)tb * 4.624972813284271f;  // ln(102)
  }
  if (tid < 16) sLogy[tid] = 0.f;
  __syncthreads();
  float a_local = 0, a_maxp = 0, c_sup = 0, c_pred = 0, c_ov = 0, c_match = 0;
  float s_predc = 0, s_ov = 0, s_match = 0;
  for (int r = tid; r < 2048; r += 256) {
    const int b = r >> 7, t = r & 127;
    const int L = y_lens[b];
    if (t < L) {
      const int yv = y[r];
      const float em_y = emission[(size_t)r * 1024 + yv];
      const float lse = row_lse[r];
      a_local += em_y - lse;
      a_maxp += expf(row_max[r] - lse);
      float term = em_y;
      if (t < L - 1) term += transition[(size_t)yv * 1024 + y[r + 1]];
      atomicAdd(&sLogy[b], term);
      const float ypos = (yv > 0) ? 1.f : 0.f;
      c_sup += ypos;
      const int cs = (int)out_crf[r];
      c_pred += (cs > 0) ? 1.f : 0.f;
      c_ov += ((cs > 0) && (yv > 0)) ? 1.f : 0.f;
      c_match += (cs == yv) ? 1.f : 0.f;
      const int ss = sm_pred[r];
      s_predc += (ss > 0) ? 1.f : 0.f;
      s_ov += ((ss > 0) && (yv > 0)) ? 1.f : 0.f;
      s_match += (ss == yv) ? 1.f : 0.f;
    }
  }
  __syncthreads();
  a_local = blk_sum(a_local, rb, tid);
  a_maxp = blk_sum(a_maxp, rb, tid);
  c_sup = blk_sum(c_sup, rb, tid);
  c_pred = blk_sum(c_pred, rb, tid);
  c_ov = blk_sum(c_ov, rb, tid);
  c_match = blk_sum(c_match, rb, tid);
  s_predc = blk_sum(s_predc, rb, tid);
  s_ov = blk_sum(s_ov, rb, tid);
  s_match = blk_sum(s_match, rb, tid);
  if (tid == 0) {
    float tl = 0.f;
    for (int b = 0; b < 16; ++b) tl += (float)y_lens[b];
    float mZ = 0, mZa = 0, dE = 0, dA = 0;
    for (int b = 0; b < 16; ++b) {
      mZ += sZ[b]; mZa += sZa[b];
      dE += sLogy[b] - sZ[b];
      dA += sLogy[b] - sZa[b];
    }
    mZ *= (1.f / 16.f); mZa *= (1.f / 16.f);
    const float sle = -dE * (1.f / 16.f);
    const float sla = -dA * (1.f / 16.f);
    const float slocal = a_local / tl;
    const float maxp = a_maxp / tl;
    const float loss = sla + 0.1f * slocal;
    const float crf_acc = c_match / tl;
    const float crf_prec = (c_pred > 0.f) ? (c_ov / fmaxf(c_pred, 1.f)) : 0.f;
    const float crf_recl = c_ov / fmaxf(c_sup, 1.f);
    const float crf_f1 = (crf_prec > 0.f)
        ? (2.f * crf_prec * crf_recl / fmaxf(crf_prec + crf_recl, 1e-12f)) : 0.f;
    const float sm_acc = s_match / tl;
    const float sm_prec = (s_predc > 0.f) ? (s_ov / fmaxf(s_predc, 1.f)) : 0.f;
    const float sm_recl = s_ov / fmaxf(c_sup, 1.f);
    const float sm_f1 = (sm_prec > 0.f)
        ? (2.f * sm_prec * sm_recl / fmaxf(sm_prec + sm_recl, 1e-12f)) : 0.f;
    d_out[0] = loss;
    d_out[2049] = mZ;
    d_out[2050] = mZa;
    d_out[2051] = sle;
    d_out[2052] = slocal;
    d_out[2053] = maxp;
    d_out[2054] = crf_acc;
    d_out[2055] = crf_f1;
    d_out[2056] = sm_acc;
    d_out[2057] = sm_f1;
  }
}

extern "C" void kernel_launch(void* const* d_in, const int* in_sizes, int n_in,
                              void* d_out, int out_size, void* d_ws, size_t ws_size,
                              hipStream_t stream) {
  const float* x = (const float*)d_in[0];
  const float* stm = (const float*)d_in[1];
  const int* y = (const int*)d_in[2];
  const int* yl = (const int*)d_in[3];
  float* out = (float*)d_out;
  float* ws = (float*)d_ws;

  float* emission = ws + OFF_EM;
  float* transition = ws + OFF_TR;
  unsigned short* expTb = (unsigned short*)(ws + OFF_EXPTB);
  float* u_pp = ws + OFF_UPP;
  float* av_pp = ws + OFF_APP;
  float* u_last = ws + OFF_ULST;
  float* av_last = ws + OFF_ALST;
  float* ua_last = ws + OFF_UALST;
  float* em_top = ws + OFF_ETOP;
  int* top_idx = (int*)(ws + OFF_ITOP);
  float* row_max = ws + OFF_RMAX;
  float* row_lse = ws + OFF_RLSE;
  int* sm_pred = (int*)(ws + OFF_SMP);
  int* bp = (int*)(ws + OFF_BP);
  unsigned* bars = (unsigned*)(ws + OFF_BAR);

  (void)hipMemsetAsync(bars, 0, 256, stream);
  gemm_kernel<<<dim3(48, 16), 256, 0, stream>>>(x, stm, emission, transition, expTb);
  topk_kernel<<<2048, 256, 0, stream>>>(emission, em_top, top_idx, row_max, row_lse, sm_pred);
  scan_kernel<<<528, 256, 0, stream>>>(emission, transition, expTb, em_top, top_idx,
                                       yl, u_pp, av_pp, u_last, av_last, ua_last,
                                       bp, bars, out + 1);
  finalize_kernel<<<1, 256, 0, stream>>>(emission, transition, u_last, ua_last,
                                         row_max, row_lse, sm_pred, y, yl, out);
}

// Round 8
// 1988.349 us; speedup vs baseline: 3.0914x; 3.0914x over previous
//
#include <hip/hip_runtime.h>
#include <cstdint>
#include <cstddef>

typedef unsigned long long ull;
typedef unsigned int uint32;

// B=16, T=128, K=1024, D=768, KP=102
// Persistent scan (R6 structure) + padded barrier counters (1 per 128B line).
//  fwd: 128 blocks (b*8+s), 128 cols each, expT bf16 slice
//  vit: 128 blocks (b*8+s), 128 cols each, tr fp32 slice (exact)
//  approx: 16 block-local.
// Cross-block state via sc0sc1 bypass (LLC); barrier = wave0 vmcnt drain +
// RELAXED add + RELAXED spin; each counter on its own cacheline.

// ---- workspace layout (float offsets) ----
#define OFF_EM    ((size_t)0)         // emission   2048*1024 f32
#define OFF_TR    ((size_t)2097152)   // transition 1024*1024 f32
#define OFF_EXPTB ((size_t)3145728)   // expTb      1024*1024 bf16 (ushort)
#define OFF_UPP   ((size_t)3670016)   // u ping-pong 2*16*1024
#define OFF_APP   ((size_t)3702784)   // av ping-pong 2*16*1024
#define OFF_ULST  ((size_t)3735552)   // u at t=tb   16*1024
#define OFF_ALST  ((size_t)3751936)   // av at t=tb  16*1024
#define OFF_UALST ((size_t)3768320)   // ua at t=tb  16*102
#define OFF_ETOP  ((size_t)3769952)   // em_top      2048*102
#define OFF_ITOP  ((size_t)3978848)   // top_idx     2048*102 (int)
#define OFF_RMAX  ((size_t)4187744)   // row_max     2048
#define OFF_RLSE  ((size_t)4189792)   // row_lse     2048
#define OFF_SMP   ((size_t)4191840)   // sm_pred     2048 (int)
#define OFF_BP    ((size_t)4193888)   // bp          128*16*1024 (int)
#define OFF_BAR   ((size_t)6291040)   // barrier counters (32 x 32 uints, 4KB)

#define BAR_STRIDE 32   // uints per counter = 128B -> one LLC line each

__device__ __forceinline__ unsigned short f2bf(float f) {
  uint32 u = __builtin_bit_cast(uint32, f);
  u = (u + 0x7fffu + ((u >> 16) & 1u)) >> 16;
  return (unsigned short)u;
}
__device__ __forceinline__ float bflo(uint32 w) {
  return __builtin_bit_cast(float, w << 16);
}
__device__ __forceinline__ float bfhi(uint32 w) {
  return __builtin_bit_cast(float, w & 0xffff0000u);
}

// ---------------- GEMM: [x_emb; state] (3072x768) @ state^T -> 3072x1024 ----
__global__ __launch_bounds__(256) void gemm_kernel(
    const float* __restrict__ x, const float* __restrict__ stm,
    float* __restrict__ emission, float* __restrict__ transition,
    unsigned short* __restrict__ expTb) {
  __shared__ float As[16][68];
  __shared__ float Bs[16][68];
  const int tid = threadIdx.x;
  const int tx = tid & 15, ty = tid >> 4;
  const int m0 = blockIdx.x * 64, n0 = blockIdx.y * 64;
  const int lr = tid >> 2;
  const int lc = (tid & 3) << 2;
  float acc[4][4] = {};
  const float* aptr;
  {
    int gr = m0 + lr;
    aptr = (gr < 2048) ? (x + (size_t)gr * 768) : (stm + (size_t)(gr - 2048) * 768);
  }
  const float* bptr = stm + (size_t)(n0 + lr) * 768;
  for (int k0 = 0; k0 < 768; k0 += 16) {
    float4 a4 = *(const float4*)(aptr + k0 + lc);
    float4 b4 = *(const float4*)(bptr + k0 + lc);
    __syncthreads();
    As[lc + 0][lr] = a4.x; As[lc + 1][lr] = a4.y; As[lc + 2][lr] = a4.z; As[lc + 3][lr] = a4.w;
    Bs[lc + 0][lr] = b4.x; Bs[lc + 1][lr] = b4.y; Bs[lc + 2][lr] = b4.z; Bs[lc + 3][lr] = b4.w;
    __syncthreads();
#pragma unroll
    for (int kk = 0; kk < 16; ++kk) {
      float a[4], b[4];
#pragma unroll
      for (int q = 0; q < 4; ++q) a[q] = As[kk][ty * 4 + q];
#pragma unroll
      for (int q = 0; q < 4; ++q) b[q] = Bs[kk][tx * 4 + q];
#pragma unroll
      for (int i2 = 0; i2 < 4; ++i2)
#pragma unroll
        for (int j2 = 0; j2 < 4; ++j2) acc[i2][j2] += a[i2] * b[j2];
    }
  }
  const float rs = 0.03608439182435161f;  // 1/sqrt(768)
#pragma unroll
  for (int i2 = 0; i2 < 4; ++i2) {
    int r = m0 + ty * 4 + i2;
#pragma unroll
    for (int j2 = 0; j2 < 4; ++j2) {
      int c = n0 + tx * 4 + j2;
      float v = acc[i2][j2] * rs;
      if (r < 2048) {
        emission[(size_t)r * 1024 + c] = v;
      } else {
        size_t o = (size_t)(r - 2048) * 1024 + c;
        transition[o] = v;
        expTb[o] = f2bf(expf(v));
      }
    }
  }
}

// ---------------- per-row bitonic sort -> top-102 set, max, lse, argmax ----
__global__ __launch_bounds__(256) void topk_kernel(
    const float* __restrict__ emission, float* __restrict__ em_top,
    int* __restrict__ top_idx, float* __restrict__ row_max,
    float* __restrict__ row_lse, int* __restrict__ sm_pred) {
  __shared__ float v[1024];
  __shared__ int ix[1024];
  __shared__ float rb[256];
  const int row = blockIdx.x;
  const int tid = threadIdx.x;
  const float* e = emission + (size_t)row * 1024;
  for (int p = tid; p < 1024; p += 256) { v[p] = e[p]; ix[p] = p; }
  __syncthreads();
  for (int k = 2; k <= 1024; k <<= 1) {
    for (int j = k >> 1; j > 0; j >>= 1) {
      for (int p = tid; p < 1024; p += 256) {
        int l = p ^ j;
        if (l > p) {
          float va = v[p], vb = v[l];
          int ia = ix[p], ib = ix[l];
          bool aBefore = (va > vb) || (va == vb && ia < ib);
          bool up = ((p & k) == 0);
          if (up ? !aBefore : aBefore) { v[p] = vb; v[l] = va; ix[p] = ib; ix[l] = ia; }
        }
      }
      __syncthreads();
    }
  }
  float mx = v[0];
  float s = 0.f;
  for (int p = tid; p < 1024; p += 256) s += expf(v[p] - mx);
  rb[tid] = s; __syncthreads();
  for (int w = 128; w > 0; w >>= 1) { if (tid < w) rb[tid] += rb[tid + w]; __syncthreads(); }
  if (tid == 0) {
    row_max[row] = mx;
    row_lse[row] = mx + logf(rb[0]);
    sm_pred[row] = ix[0];
  }
  for (int p = tid; p < 102; p += 256) {
    em_top[(size_t)row * 102 + p] = v[p];
    top_idx[(size_t)row * 102 + p] = ix[p];
  }
}

// ---------------- coherence helpers ----
__device__ __forceinline__ void store_bypass2(float* p, float2 v) {
  __hip_atomic_store((ull*)p, __builtin_bit_cast(ull, v),
                     __ATOMIC_RELAXED, __HIP_MEMORY_SCOPE_AGENT);
}
__device__ __forceinline__ void store_bypass_i2(int* p, int2 v) {
  __hip_atomic_store((ull*)p, __builtin_bit_cast(ull, v),
                     __ATOMIC_RELAXED, __HIP_MEMORY_SCOPE_AGENT);
}
__device__ __forceinline__ float load_bypass_f(const float* p) {
  return __hip_atomic_load(p, __ATOMIC_RELAXED, __HIP_MEMORY_SCOPE_AGENT);
}
__device__ __forceinline__ int load_bypass_i(const int* p) {
  return __hip_atomic_load(p, __ATOMIC_RELAXED, __HIP_MEMORY_SCOPE_AGENT);
}

// Barrier: wave0 vmcnt drain (covers all bypass stores — issued by wave 0),
// RELAXED add + RELAXED spin. Counter sits on its own 128B line.
__device__ __forceinline__ void group_barrier(unsigned* ctr, unsigned target) {
  __syncthreads();
  if (threadIdx.x == 0) {
    asm volatile("s_waitcnt vmcnt(0)" ::: "memory");
    __hip_atomic_fetch_add(ctr, 1u, __ATOMIC_RELAXED, __HIP_MEMORY_SCOPE_AGENT);
    while (__hip_atomic_load(ctr, __ATOMIC_RELAXED, __HIP_MEMORY_SCOPE_AGENT) < target)
      __builtin_amdgcn_s_sleep(1);
  }
  __syncthreads();
  __atomic_signal_fence(__ATOMIC_ACQUIRE);
}

__device__ __forceinline__ void stage_batch(const float* __restrict__ src,
                                            float* __restrict__ st, int tid) {
  const ull* s8 = (const ull*)src;
  ull* l8 = (ull*)st;
  l8[tid] = __hip_atomic_load(s8 + tid, __ATOMIC_RELAXED, __HIP_MEMORY_SCOPE_AGENT);
  l8[tid + 256] = __hip_atomic_load(s8 + tid + 256, __ATOMIC_RELAXED, __HIP_MEMORY_SCOPE_AGENT);
}

// ---------------- persistent scan ----
__global__ __launch_bounds__(256, 1) void scan_kernel(
    const float* __restrict__ em, const float* __restrict__ tr,
    const unsigned short* __restrict__ expTb, const float* __restrict__ em_top,
    const int* __restrict__ top_idx, const int* __restrict__ y_lens,
    float* __restrict__ u_pp, float* __restrict__ av_pp,
    float* __restrict__ u_last, float* __restrict__ av_last,
    float* __restrict__ ua_last, int* __restrict__ bp,
    unsigned* __restrict__ bars, float* __restrict__ out_crf) {
  __shared__ float st[1024];     // staged state for my batch
  __shared__ float psv[896];
  __shared__ int psi[384];
  __shared__ float sua[2][102];
  __shared__ int sidxp[102], sidxc[102];
  __shared__ float aps[102];
  __shared__ float swv[4];
  __shared__ int swi[4];
  const int bid = blockIdx.x, tid = threadIdx.x;

  if (bid < 128) {
    // ======== forward: batch b, slice s (128 cols, bf16 expT) ========
    const int b = bid >> 3, s = bid & 7;
    const int tb = y_lens[b] - 1;
    const int tl = tid & 31, h = tid >> 5;   // 4 cols/lane, i-eighth h
    const int j = s * 128 + tl * 4;
    if (h == 0) {
      const float4 e4 = *(const float4*)(em + (size_t)(b * 128) * 1024 + j);
      float4 v;
      v.x = expf(e4.x); v.y = expf(e4.y); v.z = expf(e4.z); v.w = expf(e4.w);
      float* dst = u_pp + b * 1024 + j;
      store_bypass2(dst, make_float2(v.x, v.y));
      store_bypass2(dst + 2, make_float2(v.z, v.w));
      if (tb == 0) *(float4*)(u_last + b * 1024 + j) = v;
    }
    unsigned k = 1;
    group_barrier(&bars[b * BAR_STRIDE], 8u * k); ++k;
    for (int t = 1; t < 128; ++t) {
      stage_batch(u_pp + ((t - 1) & 1) * 16384 + b * 1024, st, tid);
      __syncthreads();
      float a0 = 0.f, a1 = 0.f, a2 = 0.f, a3 = 0.f;
#pragma unroll 4
      for (int i = h * 128; i < h * 128 + 128; ++i) {
        const uint2 w = *(const uint2*)(expTb + (size_t)i * 1024 + j);
        const float ui = st[i];
        a0 += ui * bflo(w.x); a1 += ui * bfhi(w.x);
        a2 += ui * bflo(w.y); a3 += ui * bfhi(w.y);
      }
      if (h) {
        float* p = psv + (h - 1) * 128 + tl * 4;
        p[0] = a0; p[1] = a1; p[2] = a2; p[3] = a3;
      }
      __syncthreads();
      if (h == 0) {
#pragma unroll
        for (int q = 0; q < 7; ++q) {
          const float* p = psv + q * 128 + tl * 4;
          a0 += p[0]; a1 += p[1]; a2 += p[2]; a3 += p[3];
        }
        const float4 e4 = *(const float4*)(em + ((size_t)b * 128 + t) * 1024 + j);
        float4 v;
        v.x = a0 * expf(e4.x) * (1.0f / 1024.0f);
        v.y = a1 * expf(e4.y) * (1.0f / 1024.0f);
        v.z = a2 * expf(e4.z) * (1.0f / 1024.0f);
        v.w = a3 * expf(e4.w) * (1.0f / 1024.0f);
        float* dst = u_pp + (t & 1) * 16384 + b * 1024 + j;
        store_bypass2(dst, make_float2(v.x, v.y));
        store_bypass2(dst + 2, make_float2(v.z, v.w));
        if (t == tb) *(float4*)(u_last + b * 1024 + j) = v;
      }
      group_barrier(&bars[b * BAR_STRIDE], 8u * k); ++k;
    }
  } else if (bid < 256) {
    // ======== viterbi: batch b, slice s (128 cols, fp32 tr) ========
    const int local = bid - 128;
    const int b = local >> 3, s = local & 7;
    const int tb = y_lens[b] - 1;
    const int tl = tid & 63, h = tid >> 6;   // 2 cols/lane, i-quarter h
    const int j = s * 128 + tl * 2;
    if (h == 0) {
      const float2 e2 = *(const float2*)(em + (size_t)(b * 128) * 1024 + j);
      store_bypass2(av_pp + b * 1024 + j, e2);
      if (tb == 0) store_bypass2(av_last + b * 1024 + j, e2);
    }
    unsigned k = 1;
    group_barrier(&bars[(16 + b) * BAR_STRIDE], 8u * k); ++k;
    for (int t = 1; t < 128; ++t) {
      stage_batch(av_pp + ((t - 1) & 1) * 16384 + b * 1024, st, tid);
      __syncthreads();
      float m0 = -3.0e38f, m1 = -3.0e38f;
      int x0 = 0x7fffffff, x1 = 0x7fffffff;
#pragma unroll 4
      for (int i = h * 256; i < h * 256 + 256; ++i) {
        const float2 t2 = *(const float2*)(tr + (size_t)i * 1024 + j);
        const float ai = st[i];
        float c0 = ai + t2.x;
        float c1 = ai + t2.y;
        if (c0 > m0) { m0 = c0; x0 = i; }
        if (c1 > m1) { m1 = c1; x1 = i; }
      }
      if (h) {
        psv[(h - 1) * 128 + tl * 2] = m0; psv[(h - 1) * 128 + tl * 2 + 1] = m1;
        psi[(h - 1) * 128 + tl * 2] = x0; psi[(h - 1) * 128 + tl * 2 + 1] = x1;
      }
      __syncthreads();
      if (h == 0) {
#pragma unroll
        for (int q = 0; q < 3; ++q) {
          float p0 = psv[q * 128 + tl * 2], p1 = psv[q * 128 + tl * 2 + 1];
          int y0 = psi[q * 128 + tl * 2], y1 = psi[q * 128 + tl * 2 + 1];
          if (p0 > m0) { m0 = p0; x0 = y0; }  // ties keep lower h = lower i
          if (p1 > m1) { m1 = p1; x1 = y1; }
        }
        const float2 e2 = *(const float2*)(em + ((size_t)b * 128 + t) * 1024 + j);
        float2 nv = make_float2(m0 + e2.x, m1 + e2.y);
        store_bypass2(av_pp + (t & 1) * 16384 + b * 1024 + j, nv);
        store_bypass_i2(bp + (size_t)t * 16384 + b * 1024 + j, make_int2(x0, x1));
        if (t == tb) store_bypass2(av_last + b * 1024 + j, nv);
      }
      group_barrier(&bars[(16 + b) * BAR_STRIDE], 8u * k); ++k;
    }
    // ---- backtrace: one block per batch (slice 0); bypass reads ----
    if (s == 0) {
      const int tbb = tb;
      for (int t2 = tbb + 1 + tid; t2 < 128; t2 += 256) out_crf[b * 128 + t2] = 0.f;
      const float* al = av_last + b * 1024;
      float bv = -3.0e38f;
      int bi = 0x7fffffff;
      for (int i = tid; i < 1024; i += 256) {
        float val = load_bypass_f(al + i);
        if (val > bv || (val == bv && i < bi)) { bv = val; bi = i; }
      }
      for (int off = 32; off > 0; off >>= 1) {
        float ov = __shfl_xor(bv, off);
        int oi = __shfl_xor(bi, off);
        if (ov > bv || (ov == bv && oi < bi)) { bv = ov; bi = oi; }
      }
      if ((tid & 63) == 0) { swv[tid >> 6] = bv; swi[tid >> 6] = bi; }
      __syncthreads();
      if (tid == 0) {
        for (int q = 1; q < 4; ++q)
          if (swv[q] > bv || (swv[q] == bv && swi[q] < bi)) { bv = swv[q]; bi = swi[q]; }
        int sx = bi;
        out_crf[b * 128 + tbb] = (float)sx;
        for (int t2 = tbb - 1; t2 >= 0; --t2) {
          sx = load_bypass_i(bp + (size_t)(t2 + 1) * 16384 + b * 1024 + sx);
          out_crf[b * 128 + t2] = (float)sx;
        }
      }
    }
  } else {
    // ======== approx: one block per batch, fully block-local ========
    const int b = bid - 256;
    const int tb = y_lens[b] - 1;
    const int j2 = tid & 127, h2 = tid >> 7;
    if (tid < 102) {
      float v = expf(em_top[(size_t)(b * 128) * 102 + tid]);
      sua[0][tid] = v;
      if (tb == 0) ua_last[b * 102 + tid] = v;
    }
    __syncthreads();
    for (int t = 1; t < 128; ++t) {
      if (tid < 102) {
        sidxp[tid] = top_idx[((size_t)b * 128 + (t - 1)) * 102 + tid];
        sidxc[tid] = top_idx[((size_t)b * 128 + t) * 102 + tid];
      }
      __syncthreads();
      float acc2 = 0.f;
      if (j2 < 102) {
        const int col = sidxc[j2];
        const float* up = sua[(t - 1) & 1];
        for (int i = h2 * 51; i < h2 * 51 + 51; ++i)
          acc2 += up[i] * bflo((uint32)expTb[(size_t)sidxp[i] * 1024 + col]);
      }
      if (h2 == 1 && j2 < 102) aps[j2] = acc2;
      __syncthreads();
      if (h2 == 0 && j2 < 102) {
        acc2 += aps[j2];
        float e = em_top[((size_t)b * 128 + t) * 102 + j2];
        float nv = acc2 * expf(e) * (1.0f / 102.0f);
        sua[t & 1][j2] = nv;
        if (t == tb) ua_last[b * 102 + j2] = nv;
      }
      __syncthreads();
    }
  }
}

// ---------------- scalars & metrics ----
__device__ __forceinline__ float blk_sum(float v, float* rb, int tid) {
  rb[tid] = v; __syncthreads();
  for (int w = 128; w > 0; w >>= 1) { if (tid < w) rb[tid] += rb[tid + w]; __syncthreads(); }
  float r = rb[0]; __syncthreads();
  return r;
}

__global__ __launch_bounds__(256) void finalize_kernel(
    const float* __restrict__ emission, const float* __restrict__ transition,
    const float* __restrict__ u_last, const float* __restrict__ ua_last,
    const float* __restrict__ row_max, const float* __restrict__ row_lse,
    const int* __restrict__ sm_pred, const int* __restrict__ y,
    const int* __restrict__ y_lens, float* __restrict__ d_out) {
  __shared__ float rb[256];
  __shared__ float sZ[16], sZa[16], sLogy[16];
  const int tid = threadIdx.x;
  const float* out_crf = d_out + 1;
  for (int b = 0; b < 16; ++b) {
    const int tb = y_lens[b] - 1;
    float p = 0.f;
    for (int i = tid; i < 1024; i += 256) p += u_last[(size_t)b * 1024 + i];
    p = blk_sum(p, rb, tid);
    if (tid == 0) sZ[b] = logf(p) + (float)tb * 6.931471805599453f;  // ln(1024)
    float q = 0.f;
    for (int i = tid; i < 102; i += 256) q += ua_last[(size_t)b * 102 + i];
    q = blk_sum(q, rb, tid);
    if (tid == 0) sZa[b] = logf(q) + (float)tb * 4.624972813284271f;  // ln(102)
  }
  if (tid < 16) sLogy[tid] = 0.f;
  __syncthreads();
  float a_local = 0, a_maxp = 0, c_sup = 0, c_pred = 0, c_ov = 0, c_match = 0;
  float s_predc = 0, s_ov = 0, s_match = 0;
  for (int r = tid; r < 2048; r += 256) {
    const int b = r >> 7, t = r & 127;
    const int L = y_lens[b];
    if (t < L) {
      const int yv = y[r];
      const float em_y = emission[(size_t)r * 1024 + yv];
      const float lse = row_lse[r];
      a_local += em_y - lse;
      a_maxp += expf(row_max[r] - lse);
      float term = em_y;
      if (t < L - 1) term += transition[(size_t)yv * 1024 + y[r + 1]];
      atomicAdd(&sLogy[b], term);
      const float ypos = (yv > 0) ? 1.f : 0.f;
      c_sup += ypos;
      const int cs = (int)out_crf[r];
      c_pred += (cs > 0) ? 1.f : 0.f;
      c_ov += ((cs > 0) && (yv > 0)) ? 1.f : 0.f;
      c_match += (cs == yv) ? 1.f : 0.f;
      const int ss = sm_pred[r];
      s_predc += (ss > 0) ? 1.f : 0.f;
      s_ov += ((ss > 0) && (yv > 0)) ? 1.f : 0.f;
      s_match += (ss == yv) ? 1.f : 0.f;
    }
  }
  __syncthreads();
  a_local = blk_sum(a_local, rb, tid);
  a_maxp = blk_sum(a_maxp, rb, tid);
  c_sup = blk_sum(c_sup, rb, tid);
  c_pred = blk_sum(c_pred, rb, tid);
  c_ov = blk_sum(c_ov, rb, tid);
  c_match = blk_sum(c_match, rb, tid);
  s_predc = blk_sum(s_predc, rb, tid);
  s_ov = blk_sum(s_ov, rb, tid);
  s_match = blk_sum(s_match, rb, tid);
  if (tid == 0) {
    float tl = 0.f;
    for (int b = 0; b < 16; ++b) tl += (float)y_lens[b];
    float mZ = 0, mZa = 0, dE = 0, dA = 0;
    for (int b = 0; b < 16; ++b) {
      mZ += sZ[b]; mZa += sZa[b];
      dE += sLogy[b] - sZ[b];
      dA += sLogy[b] - sZa[b];
    }
    mZ *= (1.f / 16.f); mZa *= (1.f / 16.f);
    const float sle = -dE * (1.f / 16.f);
    const float sla = -dA * (1.f / 16.f);
    const float slocal = a_local / tl;
    const float maxp = a_maxp / tl;
    const float loss = sla + 0.1f * slocal;
    const float crf_acc = c_match / tl;
    const float crf_prec = (c_pred > 0.f) ? (c_ov / fmaxf(c_pred, 1.f)) : 0.f;
    const float crf_recl = c_ov / fmaxf(c_sup, 1.f);
    const float crf_f1 = (crf_prec > 0.f)
        ? (2.f * crf_prec * crf_recl / fmaxf(crf_prec + crf_recl, 1e-12f)) : 0.f;
    const float sm_acc = s_match / tl;
    const float sm_prec = (s_predc > 0.f) ? (s_ov / fmaxf(s_predc, 1.f)) : 0.f;
    const float sm_recl = s_ov / fmaxf(c_sup, 1.f);
    const float sm_f1 = (sm_prec > 0.f)
        ? (2.f * sm_prec * sm_recl / fmaxf(sm_prec + sm_recl, 1e-12f)) : 0.f;
    d_out[0] = loss;
    d_out[2049] = mZ;
    d_out[2050] = mZa;
    d_out[2051] = sle;
    d_out[2052] = slocal;
    d_out[2053] = maxp;
    d_out[2054] = crf_acc;
    d_out[2055] = crf_f1;
    d_out[2056] = sm_acc;
    d_out[2057] = sm_f1;
  }
}

extern "C" void kernel_launch(void* const* d_in, const int* in_sizes, int n_in,
                              void* d_out, int out_size, void* d_ws, size_t ws_size,
                              hipStream_t stream) {
  const float* x = (const float*)d_in[0];
  const float* stm = (const float*)d_in[1];
  const int* y = (const int*)d_in[2];
  const int* yl = (const int*)d_in[3];
  float* out = (float*)d_out;
  float* ws = (float*)d_ws;

  float* emission = ws + OFF_EM;
  float* transition = ws + OFF_TR;
  unsigned short* expTb = (unsigned short*)(ws + OFF_EXPTB);
  float* u_pp = ws + OFF_UPP;
  float* av_pp = ws + OFF_APP;
  float* u_last = ws + OFF_ULST;
  float* av_last = ws + OFF_ALST;
  float* ua_last = ws + OFF_UALST;
  float* em_top = ws + OFF_ETOP;
  int* top_idx = (int*)(ws + OFF_ITOP);
  float* row_max = ws + OFF_RMAX;
  float* row_lse = ws + OFF_RLSE;
  int* sm_pred = (int*)(ws + OFF_SMP);
  int* bp = (int*)(ws + OFF_BP);
  unsigned* bars = (unsigned*)(ws + OFF_BAR);

  (void)hipMemsetAsync(bars, 0, 32 * BAR_STRIDE * sizeof(unsigned), stream);
  gemm_kernel<<<dim3(48, 16), 256, 0, stream>>>(x, stm, emission, transition, expTb);
  topk_kernel<<<2048, 256, 0, stream>>>(emission, em_top, top_idx, row_max, row_lse, sm_pred);
  scan_kernel<<<272, 256, 0, stream>>>(emission, transition, expTb, em_top, top_idx,
                                       yl, u_pp, av_pp, u_last, av_last, ua_last,
                                       bp, bars, out + 1);
  finalize_kernel<<<1, 256, 0, stream>>>(emission, transition, u_last, ua_last,
                                         row_max, row_lse, sm_pred, y, yl, out);
}

// Round 9
// 1973.892 us; speedup vs baseline: 3.1140x; 1.0073x over previous
//
#include <hip/hip_runtime.h>
#include <cstdint>
#include <cstddef>

typedef unsigned long long ull;
typedef unsigned int uint32;

// B=16, T=128, K=1024, D=768, KP=102
// Persistent scan (R8 structure) + write-once t-indexed ready flags instead of
// atomic-counter barriers: producer = bypass stores -> vmcnt drain -> flag=1
// (plain bypass store, own 64B line); consumer = 8 lanes poll step t-1 flags.
//  fwd: 128 blocks (b*8+s), 128 cols each, expT bf16 slice
//  vit: 128 blocks (b*8+s), 128 cols each, tr fp32 slice (exact)
//  approx: 16 block-local.

// ---- workspace layout (float offsets) ----
#define OFF_EM    ((size_t)0)         // emission   2048*1024 f32
#define OFF_TR    ((size_t)2097152)   // transition 1024*1024 f32
#define OFF_EXPTB ((size_t)3145728)   // expTb      1024*1024 bf16 (ushort)
#define OFF_UPP   ((size_t)3670016)   // u ping-pong 2*16*1024
#define OFF_APP   ((size_t)3702784)   // av ping-pong 2*16*1024
#define OFF_ULST  ((size_t)3735552)   // u at t=tb   16*1024
#define OFF_ALST  ((size_t)3751936)   // av at t=tb  16*1024
#define OFF_UALST ((size_t)3768320)   // ua at t=tb  16*102
#define OFF_ETOP  ((size_t)3769952)   // em_top      2048*102
#define OFF_ITOP  ((size_t)3978848)   // top_idx     2048*102 (int)
#define OFF_RMAX  ((size_t)4187744)   // row_max     2048
#define OFF_RLSE  ((size_t)4189792)   // row_lse     2048
#define OFF_SMP   ((size_t)4191840)   // sm_pred     2048 (int)
#define OFF_BP    ((size_t)4193888)   // bp          128*16*1024 (int)
#define OFF_FLG   ((size_t)6291040)   // flags 32 grp x 128 t x 8 slice x 16u = 2MB

#define FLAG_PAD 16  // uints per flag = 64B line each

__device__ __forceinline__ unsigned short f2bf(float f) {
  uint32 u = __builtin_bit_cast(uint32, f);
  u = (u + 0x7fffu + ((u >> 16) & 1u)) >> 16;
  return (unsigned short)u;
}
__device__ __forceinline__ float bflo(uint32 w) {
  return __builtin_bit_cast(float, w << 16);
}
__device__ __forceinline__ float bfhi(uint32 w) {
  return __builtin_bit_cast(float, w & 0xffff0000u);
}

// ---------------- GEMM: [x_emb; state] (3072x768) @ state^T -> 3072x1024 ----
__global__ __launch_bounds__(256) void gemm_kernel(
    const float* __restrict__ x, const float* __restrict__ stm,
    float* __restrict__ emission, float* __restrict__ transition,
    unsigned short* __restrict__ expTb) {
  __shared__ float As[16][68];
  __shared__ float Bs[16][68];
  const int tid = threadIdx.x;
  const int tx = tid & 15, ty = tid >> 4;
  const int m0 = blockIdx.x * 64, n0 = blockIdx.y * 64;
  const int lr = tid >> 2;
  const int lc = (tid & 3) << 2;
  float acc[4][4] = {};
  const float* aptr;
  {
    int gr = m0 + lr;
    aptr = (gr < 2048) ? (x + (size_t)gr * 768) : (stm + (size_t)(gr - 2048) * 768);
  }
  const float* bptr = stm + (size_t)(n0 + lr) * 768;
  for (int k0 = 0; k0 < 768; k0 += 16) {
    float4 a4 = *(const float4*)(aptr + k0 + lc);
    float4 b4 = *(const float4*)(bptr + k0 + lc);
    __syncthreads();
    As[lc + 0][lr] = a4.x; As[lc + 1][lr] = a4.y; As[lc + 2][lr] = a4.z; As[lc + 3][lr] = a4.w;
    Bs[lc + 0][lr] = b4.x; Bs[lc + 1][lr] = b4.y; Bs[lc + 2][lr] = b4.z; Bs[lc + 3][lr] = b4.w;
    __syncthreads();
#pragma unroll
    for (int kk = 0; kk < 16; ++kk) {
      float a[4], b[4];
#pragma unroll
      for (int q = 0; q < 4; ++q) a[q] = As[kk][ty * 4 + q];
#pragma unroll
      for (int q = 0; q < 4; ++q) b[q] = Bs[kk][tx * 4 + q];
#pragma unroll
      for (int i2 = 0; i2 < 4; ++i2)
#pragma unroll
        for (int j2 = 0; j2 < 4; ++j2) acc[i2][j2] += a[i2] * b[j2];
    }
  }
  const float rs = 0.03608439182435161f;  // 1/sqrt(768)
#pragma unroll
  for (int i2 = 0; i2 < 4; ++i2) {
    int r = m0 + ty * 4 + i2;
#pragma unroll
    for (int j2 = 0; j2 < 4; ++j2) {
      int c = n0 + tx * 4 + j2;
      float v = acc[i2][j2] * rs;
      if (r < 2048) {
        emission[(size_t)r * 1024 + c] = v;
      } else {
        size_t o = (size_t)(r - 2048) * 1024 + c;
        transition[o] = v;
        expTb[o] = f2bf(expf(v));
      }
    }
  }
}

// ---------------- per-row bitonic sort -> top-102 set, max, lse, argmax ----
__global__ __launch_bounds__(256) void topk_kernel(
    const float* __restrict__ emission, float* __restrict__ em_top,
    int* __restrict__ top_idx, float* __restrict__ row_max,
    float* __restrict__ row_lse, int* __restrict__ sm_pred) {
  __shared__ float v[1024];
  __shared__ int ix[1024];
  __shared__ float rb[256];
  const int row = blockIdx.x;
  const int tid = threadIdx.x;
  const float* e = emission + (size_t)row * 1024;
  for (int p = tid; p < 1024; p += 256) { v[p] = e[p]; ix[p] = p; }
  __syncthreads();
  for (int k = 2; k <= 1024; k <<= 1) {
    for (int j = k >> 1; j > 0; j >>= 1) {
      for (int p = tid; p < 1024; p += 256) {
        int l = p ^ j;
        if (l > p) {
          float va = v[p], vb = v[l];
          int ia = ix[p], ib = ix[l];
          bool aBefore = (va > vb) || (va == vb && ia < ib);
          bool up = ((p & k) == 0);
          if (up ? !aBefore : aBefore) { v[p] = vb; v[l] = va; ix[p] = ib; ix[l] = ia; }
        }
      }
      __syncthreads();
    }
  }
  float mx = v[0];
  float s = 0.f;
  for (int p = tid; p < 1024; p += 256) s += expf(v[p] - mx);
  rb[tid] = s; __syncthreads();
  for (int w = 128; w > 0; w >>= 1) { if (tid < w) rb[tid] += rb[tid + w]; __syncthreads(); }
  if (tid == 0) {
    row_max[row] = mx;
    row_lse[row] = mx + logf(rb[0]);
    sm_pred[row] = ix[0];
  }
  for (int p = tid; p < 102; p += 256) {
    em_top[(size_t)row * 102 + p] = v[p];
    top_idx[(size_t)row * 102 + p] = ix[p];
  }
}

// ---------------- coherence helpers ----
__device__ __forceinline__ void store_bypass2(float* p, float2 v) {
  __hip_atomic_store((ull*)p, __builtin_bit_cast(ull, v),
                     __ATOMIC_RELAXED, __HIP_MEMORY_SCOPE_AGENT);
}
__device__ __forceinline__ void store_bypass_i2(int* p, int2 v) {
  __hip_atomic_store((ull*)p, __builtin_bit_cast(ull, v),
                     __ATOMIC_RELAXED, __HIP_MEMORY_SCOPE_AGENT);
}
__device__ __forceinline__ float load_bypass_f(const float* p) {
  return __hip_atomic_load(p, __ATOMIC_RELAXED, __HIP_MEMORY_SCOPE_AGENT);
}
__device__ __forceinline__ int load_bypass_i(const int* p) {
  return __hip_atomic_load(p, __ATOMIC_RELAXED, __HIP_MEMORY_SCOPE_AGENT);
}

// Producer arrival: drain wave-0's bypass stores, then set my ready flag
// (plain bypass store to a private 64B line — no RMW, no contention).
__device__ __forceinline__ void flag_set(unsigned* f) {
  asm volatile("s_waitcnt vmcnt(0)" ::: "memory");
  __hip_atomic_store(f, 1u, __ATOMIC_RELAXED, __HIP_MEMORY_SCOPE_AGENT);
}
// Consumer: lanes 0..7 poll slice flags (read-only line, one transition).
__device__ __forceinline__ void flag_poll(const unsigned* f) {
  while (__hip_atomic_load(f, __ATOMIC_RELAXED, __HIP_MEMORY_SCOPE_AGENT) == 0u)
    __builtin_amdgcn_s_sleep(1);
}

__device__ __forceinline__ void stage_batch(const float* __restrict__ src,
                                            float* __restrict__ st, int tid) {
  const ull* s8 = (const ull*)src;
  ull* l8 = (ull*)st;
  l8[tid] = __hip_atomic_load(s8 + tid, __ATOMIC_RELAXED, __HIP_MEMORY_SCOPE_AGENT);
  l8[tid + 256] = __hip_atomic_load(s8 + tid + 256, __ATOMIC_RELAXED, __HIP_MEMORY_SCOPE_AGENT);
}

// flag address: ((grp*128 + t)*8 + slice) * FLAG_PAD
__device__ __forceinline__ unsigned* flag_at(unsigned* base, int grp, int t, int s) {
  return base + ((size_t)(grp * 128 + t) * 8 + s) * FLAG_PAD;
}

// ---------------- persistent scan ----
__global__ __launch_bounds__(256, 1) void scan_kernel(
    const float* __restrict__ em, const float* __restrict__ tr,
    const unsigned short* __restrict__ expTb, const float* __restrict__ em_top,
    const int* __restrict__ top_idx, const int* __restrict__ y_lens,
    float* __restrict__ u_pp, float* __restrict__ av_pp,
    float* __restrict__ u_last, float* __restrict__ av_last,
    float* __restrict__ ua_last, int* __restrict__ bp,
    unsigned* __restrict__ flags, float* __restrict__ out_crf) {
  __shared__ float st[1024];     // staged state for my batch
  __shared__ float psv[896];
  __shared__ int psi[384];
  __shared__ float sua[2][102];
  __shared__ int sidxp[102], sidxc[102];
  __shared__ float aps[102];
  __shared__ float swv[4];
  __shared__ int swi[4];
  const int bid = blockIdx.x, tid = threadIdx.x;

  if (bid < 128) {
    // ======== forward: batch b, slice s (128 cols, bf16 expT) ========
    const int b = bid >> 3, s = bid & 7;
    const int grp = b;
    const int tb = y_lens[b] - 1;
    const int tl = tid & 31, h = tid >> 5;   // 4 cols/lane, i-eighth h
    const int j = s * 128 + tl * 4;
    if (h == 0) {
      const float4 e4 = *(const float4*)(em + (size_t)(b * 128) * 1024 + j);
      float4 v;
      v.x = expf(e4.x); v.y = expf(e4.y); v.z = expf(e4.z); v.w = expf(e4.w);
      float* dst = u_pp + b * 1024 + j;
      store_bypass2(dst, make_float2(v.x, v.y));
      store_bypass2(dst + 2, make_float2(v.z, v.w));
      if (tb == 0) *(float4*)(u_last + b * 1024 + j) = v;
    }
    if (tid == 0) flag_set(flag_at(flags, grp, 0, s));
    for (int t = 1; t < 128; ++t) {
      if (tid < 8) flag_poll(flag_at(flags, grp, t - 1, tid));
      __syncthreads();
      stage_batch(u_pp + ((t - 1) & 1) * 16384 + b * 1024, st, tid);
      __syncthreads();
      float a0 = 0.f, a1 = 0.f, a2 = 0.f, a3 = 0.f;
#pragma unroll 4
      for (int i = h * 128; i < h * 128 + 128; ++i) {
        const uint2 w = *(const uint2*)(expTb + (size_t)i * 1024 + j);
        const float ui = st[i];
        a0 += ui * bflo(w.x); a1 += ui * bfhi(w.x);
        a2 += ui * bflo(w.y); a3 += ui * bfhi(w.y);
      }
      if (h) {
        float* p = psv + (h - 1) * 128 + tl * 4;
        p[0] = a0; p[1] = a1; p[2] = a2; p[3] = a3;
      }
      __syncthreads();
      if (h == 0) {
#pragma unroll
        for (int q = 0; q < 7; ++q) {
          const float* p = psv + q * 128 + tl * 4;
          a0 += p[0]; a1 += p[1]; a2 += p[2]; a3 += p[3];
        }
        const float4 e4 = *(const float4*)(em + ((size_t)b * 128 + t) * 1024 + j);
        float4 v;
        v.x = a0 * expf(e4.x) * (1.0f / 1024.0f);
        v.y = a1 * expf(e4.y) * (1.0f / 1024.0f);
        v.z = a2 * expf(e4.z) * (1.0f / 1024.0f);
        v.w = a3 * expf(e4.w) * (1.0f / 1024.0f);
        float* dst = u_pp + (t & 1) * 16384 + b * 1024 + j;
        store_bypass2(dst, make_float2(v.x, v.y));
        store_bypass2(dst + 2, make_float2(v.z, v.w));
        if (t == tb) *(float4*)(u_last + b * 1024 + j) = v;
      }
      if (tid == 0) flag_set(flag_at(flags, grp, t, s));
    }
  } else if (bid < 256) {
    // ======== viterbi: batch b, slice s (128 cols, fp32 tr) ========
    const int local = bid - 128;
    const int b = local >> 3, s = local & 7;
    const int grp = 16 + b;
    const int tb = y_lens[b] - 1;
    const int tl = tid & 63, h = tid >> 6;   // 2 cols/lane, i-quarter h
    const int j = s * 128 + tl * 2;
    if (h == 0) {
      const float2 e2 = *(const float2*)(em + (size_t)(b * 128) * 1024 + j);
      store_bypass2(av_pp + b * 1024 + j, e2);
      if (tb == 0) store_bypass2(av_last + b * 1024 + j, e2);
    }
    if (tid == 0) flag_set(flag_at(flags, grp, 0, s));
    for (int t = 1; t < 128; ++t) {
      if (tid < 8) flag_poll(flag_at(flags, grp, t - 1, tid));
      __syncthreads();
      stage_batch(av_pp + ((t - 1) & 1) * 16384 + b * 1024, st, tid);
      __syncthreads();
      float m0 = -3.0e38f, m1 = -3.0e38f;
      int x0 = 0x7fffffff, x1 = 0x7fffffff;
#pragma unroll 4
      for (int i = h * 256; i < h * 256 + 256; ++i) {
        const float2 t2 = *(const float2*)(tr + (size_t)i * 1024 + j);
        const float ai = st[i];
        float c0 = ai + t2.x;
        float c1 = ai + t2.y;
        if (c0 > m0) { m0 = c0; x0 = i; }
        if (c1 > m1) { m1 = c1; x1 = i; }
      }
      if (h) {
        psv[(h - 1) * 128 + tl * 2] = m0; psv[(h - 1) * 128 + tl * 2 + 1] = m1;
        psi[(h - 1) * 128 + tl * 2] = x0; psi[(h - 1) * 128 + tl * 2 + 1] = x1;
      }
      __syncthreads();
      if (h == 0) {
#pragma unroll
        for (int q = 0; q < 3; ++q) {
          float p0 = psv[q * 128 + tl * 2], p1 = psv[q * 128 + tl * 2 + 1];
          int y0 = psi[q * 128 + tl * 2], y1 = psi[q * 128 + tl * 2 + 1];
          if (p0 > m0) { m0 = p0; x0 = y0; }  // ties keep lower h = lower i
          if (p1 > m1) { m1 = p1; x1 = y1; }
        }
        const float2 e2 = *(const float2*)(em + ((size_t)b * 128 + t) * 1024 + j);
        float2 nv = make_float2(m0 + e2.x, m1 + e2.y);
        store_bypass2(av_pp + (t & 1) * 16384 + b * 1024 + j, nv);
        store_bypass_i2(bp + (size_t)t * 16384 + b * 1024 + j, make_int2(x0, x1));
        if (t == tb) store_bypass2(av_last + b * 1024 + j, nv);
      }
      if (tid == 0) flag_set(flag_at(flags, grp, t, s));
    }
    // ---- backtrace: slice-0 block; wait for all slices' step-127 flags ----
    if (s == 0) {
      if (tid < 8) flag_poll(flag_at(flags, grp, 127, tid));
      __syncthreads();
      const int tbb = tb;
      for (int t2 = tbb + 1 + tid; t2 < 128; t2 += 256) out_crf[b * 128 + t2] = 0.f;
      const float* al = av_last + b * 1024;
      float bv = -3.0e38f;
      int bi = 0x7fffffff;
      for (int i = tid; i < 1024; i += 256) {
        float val = load_bypass_f(al + i);
        if (val > bv || (val == bv && i < bi)) { bv = val; bi = i; }
      }
      for (int off = 32; off > 0; off >>= 1) {
        float ov = __shfl_xor(bv, off);
        int oi = __shfl_xor(bi, off);
        if (ov > bv || (ov == bv && oi < bi)) { bv = ov; bi = oi; }
      }
      if ((tid & 63) == 0) { swv[tid >> 6] = bv; swi[tid >> 6] = bi; }
      __syncthreads();
      if (tid == 0) {
        for (int q = 1; q < 4; ++q)
          if (swv[q] > bv || (swv[q] == bv && swi[q] < bi)) { bv = swv[q]; bi = swi[q]; }
        int sx = bi;
        out_crf[b * 128 + tbb] = (float)sx;
        for (int t2 = tbb - 1; t2 >= 0; --t2) {
          sx = load_bypass_i(bp + (size_t)(t2 + 1) * 16384 + b * 1024 + sx);
          out_crf[b * 128 + t2] = (float)sx;
        }
      }
    }
  } else {
    // ======== approx: one block per batch, fully block-local ========
    const int b = bid - 256;
    const int tb = y_lens[b] - 1;
    const int j2 = tid & 127, h2 = tid >> 7;
    if (tid < 102) {
      float v = expf(em_top[(size_t)(b * 128) * 102 + tid]);
      sua[0][tid] = v;
      if (tb == 0) ua_last[b * 102 + tid] = v;
    }
    __syncthreads();
    for (int t = 1; t < 128; ++t) {
      if (tid < 102) {
        sidxp[tid] = top_idx[((size_t)b * 128 + (t - 1)) * 102 + tid];
        sidxc[tid] = top_idx[((size_t)b * 128 + t) * 102 + tid];
      }
      __syncthreads();
      float acc2 = 0.f;
      if (j2 < 102) {
        const int col = sidxc[j2];
        const float* up = sua[(t - 1) & 1];
        for (int i = h2 * 51; i < h2 * 51 + 51; ++i)
          acc2 += up[i] * bflo((uint32)expTb[(size_t)sidxp[i] * 1024 + col]);
      }
      if (h2 == 1 && j2 < 102) aps[j2] = acc2;
      __syncthreads();
      if (h2 == 0 && j2 < 102) {
        acc2 += aps[j2];
        float e = em_top[((size_t)b * 128 + t) * 102 + j2];
        float nv = acc2 * expf(e) * (1.0f / 102.0f);
        sua[t & 1][j2] = nv;
        if (t == tb) ua_last[b * 102 + j2] = nv;
      }
      __syncthreads();
    }
  }
}

// ---------------- scalars & metrics ----
__device__ __forceinline__ float blk_sum(float v, float* rb, int tid) {
  rb[tid] = v; __syncthreads();
  for (int w = 128; w > 0; w >>= 1) { if (tid < w) rb[tid] += rb[tid + w]; __syncthreads(); }
  float r = rb[0]; __syncthreads();
  return r;
}

__global__ __launch_bounds__(256) void finalize_kernel(
    const float* __restrict__ emission, const float* __restrict__ transition,
    const float* __restrict__ u_last, const float* __restrict__ ua_last,
    const float* __restrict__ row_max, const float* __restrict__ row_lse,
    const int* __restrict__ sm_pred, const int* __restrict__ y,
    const int* __restrict__ y_lens, float* __restrict__ d_out) {
  __shared__ float rb[256];
  __shared__ float sZ[16], sZa[16], sLogy[16];
  const int tid = threadIdx.x;
  const float* out_crf = d_out + 1;
  for (int b = 0; b < 16; ++b) {
    const int tb = y_lens[b] - 1;
    float p = 0.f;
    for (int i = tid; i < 1024; i += 256) p += u_last[(size_t)b * 1024 + i];
    p = blk_sum(p, rb, tid);
    if (tid == 0) sZ[b] = logf(p) + (float)tb * 6.931471805599453f;  // ln(1024)
    float q = 0.f;
    for (int i = tid; i < 102; i += 256) q += ua_last[(size_t)b * 102 + i];
    q = blk_sum(q, rb, tid);
    if (tid == 0) sZa[b] = logf(q) + (float)tb * 4.624972813284271f;  // ln(102)
  }
  if (tid < 16) sLogy[tid] = 0.f;
  __syncthreads();
  float a_local = 0, a_maxp = 0, c_sup = 0, c_pred = 0, c_ov = 0, c_match = 0;
  float s_predc = 0, s_ov = 0, s_match = 0;
  for (int r = tid; r < 2048; r += 256) {
    const int b = r >> 7, t = r & 127;
    const int L = y_lens[b];
    if (t < L) {
      const int yv = y[r];
      const float em_y = emission[(size_t)r * 1024 + yv];
      const float lse = row_lse[r];
      a_local += em_y - lse;
      a_maxp += expf(row_max[r] - lse);
      float term = em_y;
      if (t < L - 1) term += transition[(size_t)yv * 1024 + y[r + 1]];
      atomicAdd(&sLogy[b], term);
      const float ypos = (yv > 0) ? 1.f : 0.f;
      c_sup += ypos;
      const int cs = (int)out_crf[r];
      c_pred += (cs > 0) ? 1.f : 0.f;
      c_ov += ((cs > 0) && (yv > 0)) ? 1.f : 0.f;
      c_match += (cs == yv) ? 1.f : 0.f;
      const int ss = sm_pred[r];
      s_predc += (ss > 0) ? 1.f : 0.f;
      s_ov += ((ss > 0) && (yv > 0)) ? 1.f : 0.f;
      s_match += (ss == yv) ? 1.f : 0.f;
    }
  }
  __syncthreads();
  a_local = blk_sum(a_local, rb, tid);
  a_maxp = blk_sum(a_maxp, rb, tid);
  c_sup = blk_sum(c_sup, rb, tid);
  c_pred = blk_sum(c_pred, rb, tid);
  c_ov = blk_sum(c_ov, rb, tid);
  c_match = blk_sum(c_match, rb, tid);
  s_predc = blk_sum(s_predc, rb, tid);
  s_ov = blk_sum(s_ov, rb, tid);
  s_match = blk_sum(s_match, rb, tid);
  if (tid == 0) {
    float tl = 0.f;
    for (int b = 0; b < 16; ++b) tl += (float)y_lens[b];
    float mZ = 0, mZa = 0, dE = 0, dA = 0;
    for (int b = 0; b < 16; ++b) {
      mZ += sZ[b]; mZa += sZa[b];
      dE += sLogy[b] - sZ[b];
      dA += sLogy[b] - sZa[b];
    }
    mZ *= (1.f / 16.f); mZa *= (1.f / 16.f);
    const float sle = -dE * (1.f / 16.f);
    const float sla = -dA * (1.f / 16.f);
    const float slocal = a_local / tl;
    const float maxp = a_maxp / tl;
    const float loss = sla + 0.1f * slocal;
    const float crf_acc = c_match / tl;
    const float crf_prec = (c_pred > 0.f) ? (c_ov / fmaxf(c_pred, 1.f)) : 0.f;
    const float crf_recl = c_ov / fmaxf(c_sup, 1.f);
    const float crf_f1 = (crf_prec > 0.f)
        ? (2.f * crf_prec * crf_recl / fmaxf(crf_prec + crf_recl, 1e-12f)) : 0.f;
    const float sm_acc = s_match / tl;
    const float sm_prec = (s_predc > 0.f) ? (s_ov / fmaxf(s_predc, 1.f)) : 0.f;
    const float sm_recl = s_ov / fmaxf(c_sup, 1.f);
    const float sm_f1 = (sm_prec > 0.f)
        ? (2.f * sm_prec * sm_recl / fmaxf(sm_prec + sm_recl, 1e-12f)) : 0.f;
    d_out[0] = loss;
    d_out[2049] = mZ;
    d_out[2050] = mZa;
    d_out[2051] = sle;
    d_out[2052] = slocal;
    d_out[2053] = maxp;
    d_out[2054] = crf_acc;
    d_out[2055] = crf_f1;
    d_out[2056] = sm_acc;
    d_out[2057] = sm_f1;
  }
}

extern "C" void kernel_launch(void* const* d_in, const int* in_sizes, int n_in,
                              void* d_out, int out_size, void* d_ws, size_t ws_size,
                              hipStream_t stream) {
  const float* x = (const float*)d_in[0];
  const float* stm = (const float*)d_in[1];
  const int* y = (const int*)d_in[2];
  const int* yl = (const int*)d_in[3];
  float* out = (float*)d_out;
  float* ws = (float*)d_ws;

  float* emission = ws + OFF_EM;
  float* transition = ws + OFF_TR;
  unsigned short* expTb = (unsigned short*)(ws + OFF_EXPTB);
  float* u_pp = ws + OFF_UPP;
  float* av_pp = ws + OFF_APP;
  float* u_last = ws + OFF_ULST;
  float* av_last = ws + OFF_ALST;
  float* ua_last = ws + OFF_UALST;
  float* em_top = ws + OFF_ETOP;
  int* top_idx = (int*)(ws + OFF_ITOP);
  float* row_max = ws + OFF_RMAX;
  float* row_lse = ws + OFF_RLSE;
  int* sm_pred = (int*)(ws + OFF_SMP);
  int* bp = (int*)(ws + OFF_BP);
  unsigned* flags = (unsigned*)(ws + OFF_FLG);

  (void)hipMemsetAsync(flags, 0, 32 * 128 * 8 * FLAG_PAD * sizeof(unsigned), stream);
  gemm_kernel<<<dim3(48, 16), 256, 0, stream>>>(x, stm, emission, transition, expTb);
  topk_kernel<<<2048, 256, 0, stream>>>(emission, em_top, top_idx, row_max, row_lse, sm_pred);
  scan_kernel<<<272, 256, 0, stream>>>(emission, transition, expTb, em_top, top_idx,
                                       yl, u_pp, av_pp, u_last, av_last, ua_last,
                                       bp, flags, out + 1);
  finalize_kernel<<<1, 256, 0, stream>>>(emission, transition, u_last, ua_last,
                                         row_max, row_lse, sm_pred, y, yl, out);
}